// Round 6
// baseline (2143.493 us; speedup 1.0000x reference)
//
#include <hip/hip_runtime.h>
#include <math.h>

#define S_LEN  2048
#define D_DIM  1024
#define NHEAD  16
#define HDK    64
#define NBATCH 4

// ---------------------------------------------------------------------------
// Tiled fp32 GEMM: C(M x 1024) = X(M x 1024) @ W^T  (W is (1024,1024) row-major,
// used as W[n][k]).  64x64 tile, 256 threads, 4x4 per thread.
// MODE 0: RoPE + scatter to (B,H,S,DK)      (Q, K)
// MODE 1: scatter to (B,H,S,DK), no RoPE    (V)
// MODE 2: plain row-major (M x 1024)        (final @ Wo^T)
// RoPE cos/sin computed per-block into LDS (double precision, 8 entries/thread).
// ---------------------------------------------------------------------------
template<int MODE>
__global__ __launch_bounds__(256)
void proj_kernel(const float* __restrict__ X, const float* __restrict__ W,
                 const int* __restrict__ pos, float* __restrict__ out)
{
    __shared__ float As[32][68];   // [k][m], pad keeps rows 16B-aligned
    __shared__ float Bs[32][68];   // [k][n]
    __shared__ float2 cs_tab[(MODE == 0) ? 64 : 1][(MODE == 0) ? 32 : 1];

    const int t  = threadIdx.x;
    const int tr = t >> 4;         // 0..15  (row group)
    const int tc = t & 15;         // 0..15  (col group)
    const int m0 = blockIdx.y * 64;
    const int n0 = blockIdx.x * 64;

    if constexpr (MODE == 0) {
        // 64 rows x 32 freq pairs; rows are m0..m0+63 -> s = (m0+sl) mod S.
        int idx = t * 8;
#pragma unroll
        for (int u = 0; u < 8; ++u, ++idx) {
            const int sl = idx >> 5;
            const int ip = idx & 31;
            const int s  = (m0 + sl) & (S_LEN - 1);
            const double p    = (double)pos[s];
            const double invf = pow(10000.0, -(double)ip / 32.0);
            const double ang  = p * invf;
            cs_tab[sl][ip] = make_float2((float)cos(ang), (float)sin(ang));
        }
        // visibility guaranteed by the barriers inside the k-loop below
    }

    const int lr = t >> 3;         // 0..31
    const int lc = (t & 7) << 2;   // 0,4,...,28  (32-deep k-slab: this covers it)

    float acc[4][4] = {};

    for (int k0 = 0; k0 < D_DIM; k0 += 32) {
        float4 a0 = *(const float4*)&X[(size_t)(m0 + lr)      * D_DIM + k0 + lc];
        float4 a1 = *(const float4*)&X[(size_t)(m0 + lr + 32) * D_DIM + k0 + lc];
        float4 b0 = *(const float4*)&W[(size_t)(n0 + lr)      * D_DIM + k0 + lc];
        float4 b1 = *(const float4*)&W[(size_t)(n0 + lr + 32) * D_DIM + k0 + lc];
        __syncthreads();           // previous iteration's LDS reads done
        As[lc+0][lr] = a0.x; As[lc+1][lr] = a0.y; As[lc+2][lr] = a0.z; As[lc+3][lr] = a0.w;
        As[lc+0][lr+32] = a1.x; As[lc+1][lr+32] = a1.y; As[lc+2][lr+32] = a1.z; As[lc+3][lr+32] = a1.w;
        Bs[lc+0][lr] = b0.x; Bs[lc+1][lr] = b0.y; Bs[lc+2][lr] = b0.z; Bs[lc+3][lr] = b0.w;
        Bs[lc+0][lr+32] = b1.x; Bs[lc+1][lr+32] = b1.y; Bs[lc+2][lr+32] = b1.z; Bs[lc+3][lr+32] = b1.w;
        __syncthreads();
#pragma unroll
        for (int kk = 0; kk < 32; ++kk) {
            float4 av = *(const float4*)&As[kk][tr << 2];
            float4 bv = *(const float4*)&Bs[kk][tc << 2];
            float a_[4] = {av.x, av.y, av.z, av.w};
            float b_[4] = {bv.x, bv.y, bv.z, bv.w};
#pragma unroll
            for (int j = 0; j < 4; ++j)
#pragma unroll
                for (int i = 0; i < 4; ++i)
                    acc[j][i] = fmaf(a_[j], b_[i], acc[j][i]);
        }
    }

    // ---- epilogue ----
    const int dk0 = tc << 2;               // n0 % 64 == 0, so dk = tc*4 + i
#pragma unroll
    for (int j = 0; j < 4; ++j) {
        const int m = m0 + (tr << 2) + j;
        if (MODE == 2) {
            float4 res = {acc[j][0], acc[j][1], acc[j][2], acc[j][3]};
            *(float4*)&out[(size_t)m * D_DIM + n0 + dk0] = res;
        } else {
            const int b = m >> 11;            // / S_LEN
            const int s = m & (S_LEN - 1);
            const int h = n0 >> 6;
            float4 res;
            if (MODE == 0) {
                const int sl = (tr << 2) + j;             // m - m0
                float2 cs0 = cs_tab[sl][(tc << 1) + 0];   // pair index 2*tc
                float2 cs1 = cs_tab[sl][(tc << 1) + 1];   // pair index 2*tc+1
                res.x = acc[j][0] * cs0.x - acc[j][1] * cs0.y;
                res.y = acc[j][0] * cs0.y + acc[j][1] * cs0.x;
                res.z = acc[j][2] * cs1.x - acc[j][3] * cs1.y;
                res.w = acc[j][2] * cs1.y + acc[j][3] * cs1.x;
            } else {
                res = make_float4(acc[j][0], acc[j][1], acc[j][2], acc[j][3]);
            }
            *(float4*)&out[((size_t)(b * NHEAD + h) * S_LEN + s) * HDK + dk0] = res;
        }
    }
}

// ---------------------------------------------------------------------------
// Causal flash attention, fp32.  One block = 64 query rows of one (b,h).
// Q/K/V in (B,H,S,DK).  Output written directly in (B,S,D) layout.
// LDS: 3 x 64x68 fp32 = 52,224 B (P tile aliases the K tile).
// Staging: 64x64 tile = 1024 float4 -> 4 float4/thread (rows +0/+16/+32/+48).
// (Round-5 bug: previous 2-float4 staging covered only d=0..31; the d=32..63
//  half of Qs/KPs/Vs was uninitialized LDS -> garbage scores -> inf/NaN.)
// ---------------------------------------------------------------------------
__global__ __launch_bounds__(256)
void attn_kernel(const float* __restrict__ Q, const float* __restrict__ K,
                 const float* __restrict__ V, float* __restrict__ Oout)
{
    __shared__ float Qs[64][68];    // [d][r]
    __shared__ float KPs[64][68];   // phase 1: K as [d][c]; phase 2: P as [c][r]
    __shared__ float Vs[64][68];    // [c][d]

    const int t  = threadIdx.x;
    const int tr = t >> 4, tc = t & 15;
    const int qi = blockIdx.x, bh = blockIdx.y;

    const float* Qb = Q + (size_t)bh * S_LEN * HDK;
    const float* Kb = K + (size_t)bh * S_LEN * HDK;
    const float* Vb = V + (size_t)bh * S_LEN * HDK;

    const int lr4 = t >> 4;          // 0..15  (row within 16-row pass)
    const int lc4 = (t & 15) << 2;   // 0,4,...,60  (full 64-wide d coverage)

    {   // stage Q tile transposed: Qs[d][r], all 64 rows x 64 d
#pragma unroll
        for (int rr = 0; rr < 64; rr += 16) {
            float4 q = *(const float4*)&Qb[(size_t)(qi * 64 + lr4 + rr) * HDK + lc4];
            Qs[lc4+0][lr4+rr] = q.x; Qs[lc4+1][lr4+rr] = q.y;
            Qs[lc4+2][lr4+rr] = q.z; Qs[lc4+3][lr4+rr] = q.w;
        }
    }

    float o[4][4] = {};
    float mrow[4] = {-__builtin_inff(), -__builtin_inff(), -__builtin_inff(), -__builtin_inff()};
    float lrow[4] = {};

    for (int kt = 0; kt <= qi; ++kt) {
        float4 kv4[4], vv4[4];
#pragma unroll
        for (int p = 0; p < 4; ++p) {
            kv4[p] = *(const float4*)&Kb[(size_t)(kt * 64 + lr4 + p * 16) * HDK + lc4];
            vv4[p] = *(const float4*)&Vb[(size_t)(kt * 64 + lr4 + p * 16) * HDK + lc4];
        }
        __syncthreads();   // (A) prev iter's KPs/Vs reads done (also orders Qs stage on iter 0)
#pragma unroll
        for (int p = 0; p < 4; ++p) {
            const int c = lr4 + p * 16;
            KPs[lc4+0][c] = kv4[p].x; KPs[lc4+1][c] = kv4[p].y;
            KPs[lc4+2][c] = kv4[p].z; KPs[lc4+3][c] = kv4[p].w;
            *(float4*)&Vs[c][lc4] = vv4[p];
        }
        __syncthreads();   // (B)

        // S = Q K^T  (16 per thread)
        float sacc[4][4] = {};
#pragma unroll
        for (int d = 0; d < 64; ++d) {
            float4 qv = *(const float4*)&Qs[d][tr << 2];
            float4 kv = *(const float4*)&KPs[d][tc << 2];
            float q_[4] = {qv.x, qv.y, qv.z, qv.w};
            float k_[4] = {kv.x, kv.y, kv.z, kv.w};
#pragma unroll
            for (int j = 0; j < 4; ++j)
#pragma unroll
                for (int i = 0; i < 4; ++i)
                    sacc[j][i] = fmaf(q_[j], k_[i], sacc[j][i]);
        }

        // scale + causal mask + online softmax (registers + shfl only)
        const int qrow0 = qi * 64 + (tr << 2);
        const int kcol0 = kt * 64 + (tc << 2);
#pragma unroll
        for (int j = 0; j < 4; ++j) {
#pragma unroll
            for (int i = 0; i < 4; ++i) {
                float sv = sacc[j][i] * 0.125f;
                if (kcol0 + i > qrow0 + j) sv = -__builtin_inff();
                sacc[j][i] = sv;
            }
            float rm = fmaxf(fmaxf(sacc[j][0], sacc[j][1]), fmaxf(sacc[j][2], sacc[j][3]));
            rm = fmaxf(rm, __shfl_xor(rm, 1));
            rm = fmaxf(rm, __shfl_xor(rm, 2));
            rm = fmaxf(rm, __shfl_xor(rm, 4));
            rm = fmaxf(rm, __shfl_xor(rm, 8));
            const float mnew = fmaxf(mrow[j], rm);
            const float corr = (mrow[j] == -__builtin_inff()) ? 0.f : expf(mrow[j] - mnew);
            float psum = 0.f;
#pragma unroll
            for (int i = 0; i < 4; ++i) {
                float p = expf(sacc[j][i] - mnew);
                sacc[j][i] = p;
                psum += p;
            }
            psum += __shfl_xor(psum, 1);
            psum += __shfl_xor(psum, 2);
            psum += __shfl_xor(psum, 4);
            psum += __shfl_xor(psum, 8);
            lrow[j] = lrow[j] * corr + psum;
            mrow[j] = mnew;
#pragma unroll
            for (int i = 0; i < 4; ++i) o[j][i] *= corr;
        }

        __syncthreads();   // (B2) all QK^T reads of KPs done before P overwrite

        // stage P transposed into the K buffer: KPs[c][r]
#pragma unroll
        for (int j = 0; j < 4; ++j)
#pragma unroll
            for (int i = 0; i < 4; ++i)
                KPs[(tc << 2) + i][(tr << 2) + j] = sacc[j][i];
        __syncthreads();   // (C)

        // O += P @ V
#pragma unroll
        for (int c = 0; c < 64; ++c) {
            float4 pv = *(const float4*)&KPs[c][tr << 2];
            float4 vv = *(const float4*)&Vs[c][tc << 2];
            float p_[4] = {pv.x, pv.y, pv.z, pv.w};
            float v_[4] = {vv.x, vv.y, vv.z, vv.w};
#pragma unroll
            for (int j = 0; j < 4; ++j)
#pragma unroll
                for (int i = 0; i < 4; ++i)
                    o[j][i] = fmaf(p_[j], v_[i], o[j][i]);
        }
    }

    // write (B,S,D) so the final projection is a plain GEMM
    const int b = bh >> 4, h = bh & 15;
#pragma unroll
    for (int j = 0; j < 4; ++j) {
        const int srow = qi * 64 + (tr << 2) + j;
        const float inv_l = 1.0f / lrow[j];
        float4 res = {o[j][0] * inv_l, o[j][1] * inv_l, o[j][2] * inv_l, o[j][3] * inv_l};
        *(float4*)&Oout[((size_t)(b * S_LEN + srow)) * D_DIM + h * HDK + (tc << 2)] = res;
    }
}

// ---------------------------------------------------------------------------
extern "C" void kernel_launch(void* const* d_in, const int* in_sizes, int n_in,
                              void* d_out, int out_size, void* d_ws, size_t ws_size,
                              hipStream_t stream)
{
    const float* x   = (const float*)d_in[0];
    const float* Wq  = (const float*)d_in[1];
    const float* Wk  = (const float*)d_in[2];
    const float* Wv  = (const float*)d_in[3];
    const float* Wo  = (const float*)d_in[4];
    const int*   pos = (const int*)d_in[5];
    float* out = (float*)d_out;

    const size_t QKV = (size_t)NBATCH * NHEAD * S_LEN * HDK;  // 8388608 floats
    float* Qb = (float*)d_ws;          // [  0, 32) MiB
    float* Kb = Qb + QKV;              // [ 32, 64) MiB
    float* Vb = Kb + QKV;              // [ 64, 96) MiB
    float* AO = Vb + QKV;              // [ 96,128) MiB  -- total exactly 128 MiB

    dim3 blk(256);
    dim3 g1(D_DIM / 64, (NBATCH * S_LEN) / 64);   // (16, 128)
    proj_kernel<0><<<g1, blk, 0, stream>>>(x, Wq, pos, Qb);
    proj_kernel<0><<<g1, blk, 0, stream>>>(x, Wk, pos, Kb);
    proj_kernel<1><<<g1, blk, 0, stream>>>(x, Wv, pos, Vb);

    dim3 g2(S_LEN / 64, NBATCH * NHEAD);          // (32, 64)
    attn_kernel<<<g2, blk, 0, stream>>>(Qb, Kb, Vb, AO);

    proj_kernel<2><<<g1, blk, 0, stream>>>(AO, Wo, pos, out);
}

// Round 8
// 437.228 us; speedup vs baseline: 4.9025x; 4.9025x over previous
//
#include <hip/hip_runtime.h>
#include <math.h>

#define S_LEN  2048
#define D_DIM  1024
#define NHEAD  16
#define HDK    64
#define NBATCH 4

typedef __attribute__((ext_vector_type(8))) short bf16x8;   // 8 bf16 (4 VGPRs)
typedef __attribute__((ext_vector_type(4))) float f32x4;    // MFMA C/D

#define MFMA16(a, b, c) __builtin_amdgcn_mfma_f32_16x16x32_bf16((a), (b), (c), 0, 0, 0)

// MFMA 16x16x32 layout conventions used throughout (guide §3, m89/m91-verified):
//   A-frag (M=16 x K=32): lane holds row (l&15), k = (l>>4)*8 + i  (8 contiguous bf16)
//   B-frag (K=32 x N=16): lane holds col (l&15), k = (l>>4)*8 + i
//   C/D:                  lane holds col (l&15), row = (l>>4)*4 + reg

__device__ __forceinline__ unsigned short f2bf(float f) {   // RNE float->bf16
    unsigned u = __float_as_uint(f);
    u += 0x7fffu + ((u >> 16) & 1u);
    return (unsigned short)(u >> 16);
}

// ---------------------------------------------------------------------------
// fp32 -> bf16 bulk convert (vectorized, 8 elems/thread)
// ---------------------------------------------------------------------------
__global__ __launch_bounds__(256)
void convert_kernel(const float* __restrict__ src, unsigned short* __restrict__ dst, int n)
{
    int i = (blockIdx.x * 256 + threadIdx.x) * 8;
    if (i >= n) return;
    float4 f0 = *(const float4*)&src[i];
    float4 f1 = *(const float4*)&src[i + 4];
    uint4 o;
    o.x = f2bf(f0.x) | ((unsigned)f2bf(f0.y) << 16);
    o.y = f2bf(f0.z) | ((unsigned)f2bf(f0.w) << 16);
    o.z = f2bf(f1.x) | ((unsigned)f2bf(f1.y) << 16);
    o.w = f2bf(f1.z) | ((unsigned)f2bf(f1.w) << 16);
    *(uint4*)&dst[i] = o;
}

// ---------------------------------------------------------------------------
// Fused Q/K/V projection, bf16 MFMA.  C = X @ W^T, 128x128 tile, BK=32,
// 4 waves (each 64x64 = 4x4 MFMA tiles).  Grid: (24, 64); blockIdx.x>>3
// selects {Wq,Wk,Wv}.  Q/K: RoPE in fp32 acc -> scatter (B,H,S,DK) bf16.
// V: scatter transposed (B,H,DK,S) bf16 (so attn PV B-frags are contiguous).
// ---------------------------------------------------------------------------
__global__ __launch_bounds__(256)
void proj_qkv_kernel(const unsigned short* __restrict__ Xb,
                     const unsigned short* __restrict__ Wqb,
                     const unsigned short* __restrict__ Wkb,
                     const unsigned short* __restrict__ Wvb,
                     const int* __restrict__ pos,
                     unsigned short* __restrict__ Qb,
                     unsigned short* __restrict__ Kb,
                     unsigned short* __restrict__ Vtb)
{
    __shared__ short As[128][40];   // [m][k] bf16, +8 pad: row 80B (16B-aligned, 2-way reads)
    __shared__ short Bs[128][40];   // [n][k]

    const int t  = threadIdx.x;
    const int l  = t & 63;
    const int w  = t >> 6;
    const int wr = w >> 1, wc = w & 1;
    const int lm = l & 15;
    const int lk = (l >> 4) * 8;

    const int nb   = blockIdx.x;
    const int wsel = nb >> 3;
    const int n0   = (nb & 7) * 128;
    const int m0   = blockIdx.y * 128;
    const unsigned short* W = (wsel == 0) ? Wqb : (wsel == 1) ? Wkb : Wvb;

    const int sr = t >> 2;        // 0..63 staging row
    const int sc = (t & 3) * 8;   // 0,8,16,24 staging k-chunk

    f32x4 acc[4][4];
#pragma unroll
    for (int i = 0; i < 4; ++i)
#pragma unroll
        for (int j = 0; j < 4; ++j) acc[i][j] = (f32x4){0.f, 0.f, 0.f, 0.f};

    for (int k0 = 0; k0 < D_DIM; k0 += 32) {
        uint4 a0 = *(const uint4*)&Xb[(size_t)(m0 + sr)      * D_DIM + k0 + sc];
        uint4 a1 = *(const uint4*)&Xb[(size_t)(m0 + sr + 64) * D_DIM + k0 + sc];
        uint4 b0 = *(const uint4*)&W [(size_t)(n0 + sr)      * D_DIM + k0 + sc];
        uint4 b1 = *(const uint4*)&W [(size_t)(n0 + sr + 64) * D_DIM + k0 + sc];
        __syncthreads();
        *(uint4*)&As[sr][sc]      = a0;
        *(uint4*)&As[sr + 64][sc] = a1;
        *(uint4*)&Bs[sr][sc]      = b0;
        *(uint4*)&Bs[sr + 64][sc] = b1;
        __syncthreads();

        bf16x8 af[4], bf[4];
#pragma unroll
        for (int mt = 0; mt < 4; ++mt)
            af[mt] = *(const bf16x8*)&As[wr * 64 + mt * 16 + lm][lk];
#pragma unroll
        for (int nt = 0; nt < 4; ++nt)
            bf[nt] = *(const bf16x8*)&Bs[wc * 64 + nt * 16 + lm][lk];
#pragma unroll
        for (int mt = 0; mt < 4; ++mt)
#pragma unroll
            for (int nt = 0; nt < 4; ++nt)
                acc[mt][nt] = MFMA16(af[mt], bf[nt], acc[mt][nt]);
    }

    // ---- epilogue ----
    int dks[4], hs[4];
#pragma unroll
    for (int nt = 0; nt < 4; ++nt) {
        int col = n0 + wc * 64 + nt * 16 + lm;
        dks[nt] = col & 63;
        hs[nt]  = col >> 6;
    }

    if (wsel < 2) {   // Q or K: RoPE then (B,H,S,DK)
        unsigned short* Out = (wsel == 0) ? Qb : Kb;
        float invf[4];
#pragma unroll
        for (int nt = 0; nt < 4; ++nt)
            invf[nt] = exp2f((float)(dks[nt] >> 1) * -0.4152410119f);  // 10000^(-ip/32)
#pragma unroll
        for (int mt = 0; mt < 4; ++mt)
#pragma unroll
            for (int rg = 0; rg < 4; ++rg) {
                int m = m0 + wr * 64 + mt * 16 + ((l >> 4) << 2) + rg;
                int b = m >> 11, s = m & (S_LEN - 1);
                float pf = (float)pos[s];
#pragma unroll
                for (int nt = 0; nt < 4; ++nt) {
                    float sn, cn;
                    __sincosf(pf * invf[nt], &sn, &cn);
                    float val  = acc[mt][nt][rg];
                    float part = __shfl_xor(val, 1);   // adjacent column = RoPE partner
                    float res  = ((dks[nt] & 1) == 0) ? val * cn - part * sn
                                                      : part * sn + val * cn;
                    Out[((size_t)(b * NHEAD + hs[nt]) * S_LEN + s) * HDK + dks[nt]] = f2bf(res);
                }
            }
    } else {          // V: transposed (B,H,DK,S)
#pragma unroll
        for (int mt = 0; mt < 4; ++mt)
#pragma unroll
            for (int rg = 0; rg < 4; ++rg) {
                int m = m0 + wr * 64 + mt * 16 + ((l >> 4) << 2) + rg;
                int b = m >> 11, s = m & (S_LEN - 1);
#pragma unroll
                for (int nt = 0; nt < 4; ++nt)
                    Vtb[((size_t)(b * NHEAD + hs[nt]) * HDK + dks[nt]) * S_LEN + s] =
                        f2bf(acc[mt][nt][rg]);
            }
    }
}

// ---------------------------------------------------------------------------
// Causal flash attention, bf16 MFMA.  Block = 64 q-rows of one (b,h), 4 waves
// (wave w owns q-rows w*16..w*16+15).  K/V tiles 64 wide.  P staged through
// wave-private LDS rows (aliased onto the dead Q tile) -> 2 barriers/iter.
// LDS: 3 x 64x72 bf16 = 27,648 B.
// ---------------------------------------------------------------------------
__global__ __launch_bounds__(256)
void attn_kernel(const unsigned short* __restrict__ Q,
                 const unsigned short* __restrict__ K,
                 const unsigned short* __restrict__ Vt,
                 unsigned short* __restrict__ AO)
{
    __shared__ short QPs[64][72];   // prologue: Q [r][d]; loop: P [r][kcol]
    __shared__ short Ks[64][72];    // [kvrow][d]
    __shared__ short Vts[64][72];   // [d][kvrow]  (from V^T global layout)

    const int t  = threadIdx.x;
    const int l  = t & 63;
    const int w  = t >> 6;
    const int lm = l & 15;
    const int lk = (l >> 4) * 8;
    const int qi = blockIdx.x, bh = blockIdx.y;

    const unsigned short* Qbh  = Q  + (size_t)bh * S_LEN * HDK;
    const unsigned short* Kbh  = K  + (size_t)bh * S_LEN * HDK;
    const unsigned short* Vtbh = Vt + (size_t)bh * S_LEN * HDK;

    const int r0 = t >> 3;        // 0..31 staging row
    const int ch = (t & 7) * 8;   // 0..56 staging d-chunk

    {   // stage Q tile [64][64]
        uint4 q0 = *(const uint4*)&Qbh[(size_t)(qi * 64 + r0)      * HDK + ch];
        uint4 q1 = *(const uint4*)&Qbh[(size_t)(qi * 64 + r0 + 32) * HDK + ch];
        *(uint4*)&QPs[r0][ch]      = q0;
        *(uint4*)&QPs[r0 + 32][ch] = q1;
    }
    __syncthreads();

    bf16x8 aq[2];   // Q A-frags, fixed for the whole block
#pragma unroll
    for (int ks = 0; ks < 2; ++ks)
        aq[ks] = *(const bf16x8*)&QPs[w * 16 + lm][ks * 32 + lk];

    f32x4 o4[4];
#pragma unroll
    for (int dt = 0; dt < 4; ++dt) o4[dt] = (f32x4){0.f, 0.f, 0.f, 0.f};
    float mrow[4] = {-__builtin_inff(), -__builtin_inff(), -__builtin_inff(), -__builtin_inff()};
    float lrow[4] = {0.f, 0.f, 0.f, 0.f};

    for (int kt = 0; kt <= qi; ++kt) {
        uint4 k0v = *(const uint4*)&Kbh [(size_t)(kt * 64 + r0)      * HDK + ch];
        uint4 k1v = *(const uint4*)&Kbh [(size_t)(kt * 64 + r0 + 32) * HDK + ch];
        uint4 v0v = *(const uint4*)&Vtbh[(size_t)r0        * S_LEN + kt * 64 + ch];
        uint4 v1v = *(const uint4*)&Vtbh[(size_t)(r0 + 32) * S_LEN + kt * 64 + ch];
        __syncthreads();   // (A) all waves done reading Ks/Vts (and QPs aq / prev P)
        *(uint4*)&Ks[r0][ch]       = k0v;
        *(uint4*)&Ks[r0 + 32][ch]  = k1v;
        *(uint4*)&Vts[r0][ch]      = v0v;
        *(uint4*)&Vts[r0 + 32][ch] = v1v;
        __syncthreads();   // (B)

        // S = Q K^T : wave computes 16x64
        f32x4 sacc[4];
#pragma unroll
        for (int nt = 0; nt < 4; ++nt) sacc[nt] = (f32x4){0.f, 0.f, 0.f, 0.f};
#pragma unroll
        for (int nt = 0; nt < 4; ++nt)
#pragma unroll
            for (int ks = 0; ks < 2; ++ks) {
                bf16x8 bk = *(const bf16x8*)&Ks[nt * 16 + lm][ks * 32 + lk];
                sacc[nt] = MFMA16(aq[ks], bk, sacc[nt]);
            }

        // online softmax (per lane: 4 rows x 4 cols)
        const int diag = (kt == qi);
#pragma unroll
        for (int rg = 0; rg < 4; ++rg) {
            const int row_g = qi * 64 + w * 16 + ((l >> 4) << 2) + rg;
            float sv[4];
#pragma unroll
            for (int nt = 0; nt < 4; ++nt) {
                float x = sacc[nt][rg] * 0.125f;
                if (diag && (kt * 64 + nt * 16 + lm) > row_g) x = -__builtin_inff();
                sv[nt] = x;
            }
            float rm = fmaxf(fmaxf(sv[0], sv[1]), fmaxf(sv[2], sv[3]));
            rm = fmaxf(rm, __shfl_xor(rm, 1));
            rm = fmaxf(rm, __shfl_xor(rm, 2));
            rm = fmaxf(rm, __shfl_xor(rm, 4));
            rm = fmaxf(rm, __shfl_xor(rm, 8));
            const float mnew = fmaxf(mrow[rg], rm);       // finite from kt=0 on
            const float corr = __expf(mrow[rg] - mnew);   // exp(-inf)=0 first iter
            float pv[4], psum = 0.f;
#pragma unroll
            for (int nt = 0; nt < 4; ++nt) { pv[nt] = __expf(sv[nt] - mnew); psum += pv[nt]; }
            psum += __shfl_xor(psum, 1);
            psum += __shfl_xor(psum, 2);
            psum += __shfl_xor(psum, 4);
            psum += __shfl_xor(psum, 8);
            lrow[rg] = lrow[rg] * corr + psum;
            mrow[rg] = mnew;
#pragma unroll
            for (int dt = 0; dt < 4; ++dt) o4[dt][rg] *= corr;
            // stage P (bf16) into wave-private rows of QPs
#pragma unroll
            for (int nt = 0; nt < 4; ++nt)
                QPs[w * 16 + ((l >> 4) << 2) + rg][nt * 16 + lm] = (short)f2bf(pv[nt]);
        }

        // O += P V  (wave reads only its own P rows -> no barrier needed;
        // same-pointer ds_write->ds_read dependence is compiler-ordered)
#pragma unroll
        for (int ks = 0; ks < 2; ++ks) {
            bf16x8 ap = *(const bf16x8*)&QPs[w * 16 + lm][ks * 32 + lk];
#pragma unroll
            for (int dt = 0; dt < 4; ++dt) {
                bf16x8 bv = *(const bf16x8*)&Vts[dt * 16 + lm][ks * 32 + lk];
                o4[dt] = MFMA16(ap, bv, o4[dt]);
            }
        }
    }

    // epilogue: AO (B,S,D) bf16
    const int b = bh >> 4, h = bh & 15;
#pragma unroll
    for (int rg = 0; rg < 4; ++rg) {
        const int row_g = qi * 64 + w * 16 + ((l >> 4) << 2) + rg;
        const float il = 1.0f / lrow[rg];
#pragma unroll
        for (int dt = 0; dt < 4; ++dt)
            AO[((size_t)(b * S_LEN + row_g)) * D_DIM + h * HDK + dt * 16 + lm] =
                f2bf(o4[dt][rg] * il);
    }
}

// ---------------------------------------------------------------------------
// Final projection: out = AO @ Wo^T, bf16 MFMA, fp32 output (B,S,D).
// ---------------------------------------------------------------------------
__global__ __launch_bounds__(256)
void proj_out_kernel(const unsigned short* __restrict__ Ab,
                     const unsigned short* __restrict__ Wob,
                     float* __restrict__ out)
{
    __shared__ short As[128][40];
    __shared__ short Bs[128][40];

    const int t  = threadIdx.x;
    const int l  = t & 63;
    const int w  = t >> 6;
    const int wr = w >> 1, wc = w & 1;
    const int lm = l & 15;
    const int lk = (l >> 4) * 8;
    const int n0 = blockIdx.x * 128;
    const int m0 = blockIdx.y * 128;
    const int sr = t >> 2;
    const int sc = (t & 3) * 8;

    f32x4 acc[4][4];
#pragma unroll
    for (int i = 0; i < 4; ++i)
#pragma unroll
        for (int j = 0; j < 4; ++j) acc[i][j] = (f32x4){0.f, 0.f, 0.f, 0.f};

    for (int k0 = 0; k0 < D_DIM; k0 += 32) {
        uint4 a0 = *(const uint4*)&Ab [(size_t)(m0 + sr)      * D_DIM + k0 + sc];
        uint4 a1 = *(const uint4*)&Ab [(size_t)(m0 + sr + 64) * D_DIM + k0 + sc];
        uint4 b0 = *(const uint4*)&Wob[(size_t)(n0 + sr)      * D_DIM + k0 + sc];
        uint4 b1 = *(const uint4*)&Wob[(size_t)(n0 + sr + 64) * D_DIM + k0 + sc];
        __syncthreads();
        *(uint4*)&As[sr][sc]      = a0;
        *(uint4*)&As[sr + 64][sc] = a1;
        *(uint4*)&Bs[sr][sc]      = b0;
        *(uint4*)&Bs[sr + 64][sc] = b1;
        __syncthreads();

        bf16x8 af[4], bf[4];
#pragma unroll
        for (int mt = 0; mt < 4; ++mt)
            af[mt] = *(const bf16x8*)&As[wr * 64 + mt * 16 + lm][lk];
#pragma unroll
        for (int nt = 0; nt < 4; ++nt)
            bf[nt] = *(const bf16x8*)&Bs[wc * 64 + nt * 16 + lm][lk];
#pragma unroll
        for (int mt = 0; mt < 4; ++mt)
#pragma unroll
            for (int nt = 0; nt < 4; ++nt)
                acc[mt][nt] = MFMA16(af[mt], bf[nt], acc[mt][nt]);
    }

#pragma unroll
    for (int mt = 0; mt < 4; ++mt)
#pragma unroll
        for (int rg = 0; rg < 4; ++rg) {
            int m = m0 + wr * 64 + mt * 16 + ((l >> 4) << 2) + rg;
#pragma unroll
            for (int nt = 0; nt < 4; ++nt)
                out[(size_t)m * D_DIM + n0 + wc * 64 + nt * 16 + lm] = acc[mt][nt][rg];
        }
}

// ---------------------------------------------------------------------------
extern "C" void kernel_launch(void* const* d_in, const int* in_sizes, int n_in,
                              void* d_out, int out_size, void* d_ws, size_t ws_size,
                              hipStream_t stream)
{
    const float* x   = (const float*)d_in[0];
    const float* Wq  = (const float*)d_in[1];
    const float* Wk  = (const float*)d_in[2];
    const float* Wv  = (const float*)d_in[3];
    const float* Wo  = (const float*)d_in[4];
    const int*   pos = (const int*)d_in[5];
    float* out = (float*)d_out;

    const size_t NX = (size_t)NBATCH * S_LEN * D_DIM;   // 8,388,608
    const size_t NW = (size_t)D_DIM * D_DIM;            // 1,048,576

    unsigned short* Xb  = (unsigned short*)d_ws;        // ws total: 88 MB (< 128 MB)
    unsigned short* Wqb = Xb  + NX;
    unsigned short* Wkb = Wqb + NW;
    unsigned short* Wvb = Wkb + NW;
    unsigned short* Wob = Wvb + NW;
    unsigned short* Qb  = Wob + NW;
    unsigned short* Kb  = Qb  + NX;
    unsigned short* Vtb = Kb  + NX;
    unsigned short* AOb = Vtb + NX;

    dim3 blk(256);
    convert_kernel<<<dim3(4096), blk, 0, stream>>>(x,  Xb,  (int)NX);
    convert_kernel<<<dim3(512),  blk, 0, stream>>>(Wq, Wqb, (int)NW);
    convert_kernel<<<dim3(512),  blk, 0, stream>>>(Wk, Wkb, (int)NW);
    convert_kernel<<<dim3(512),  blk, 0, stream>>>(Wv, Wvb, (int)NW);
    convert_kernel<<<dim3(512),  blk, 0, stream>>>(Wo, Wob, (int)NW);

    proj_qkv_kernel<<<dim3(24, 64), blk, 0, stream>>>(Xb, Wqb, Wkb, Wvb, pos, Qb, Kb, Vtb);

    attn_kernel<<<dim3(S_LEN / 64, NBATCH * NHEAD), blk, 0, stream>>>(Qb, Kb, Vtb, AOb);

    proj_out_kernel<<<dim3(8, 64), blk, 0, stream>>>(AOb, Wob, out);
}

// Round 9
// 401.071 us; speedup vs baseline: 5.3444x; 1.0902x over previous
//
#include <hip/hip_runtime.h>
#include <math.h>

#define S_LEN  2048
#define D_DIM  1024
#define NHEAD  16
#define HDK    64
#define NBATCH 4

typedef __attribute__((ext_vector_type(8))) short bf16x8;   // 8 bf16 (4 VGPRs)
typedef __attribute__((ext_vector_type(4))) float f32x4;    // MFMA C/D

#define MFMA16(a, b, c) __builtin_amdgcn_mfma_f32_16x16x32_bf16((a), (b), (c), 0, 0, 0)

// MFMA 16x16x32 layouts (guide §3, m89/m91-verified):
//   A-frag: lane holds row (l&15), k = (l>>4)*8 + i (8 contiguous bf16)
//   B-frag: lane holds col (l&15), k = (l>>4)*8 + i
//   C/D:    lane holds col (l&15), row = (l>>4)*4 + reg

__device__ __forceinline__ unsigned short f2bf(float f) {   // RNE float->bf16
    unsigned u = __float_as_uint(f);
    u += 0x7fffu + ((u >> 16) & 1u);
    return (unsigned short)(u >> 16);
}

// Barrier that does NOT drain vmcnt: prefetch global->reg loads stay in
// flight across it.  lgkmcnt(0) makes this wave's ds_writes visible first.
// Safe because the only memory crossing the barrier unwaited is loads to
// private VGPRs (no cross-thread visibility requirement).
__device__ __forceinline__ void barrier_keep_vmem() {
    asm volatile("s_waitcnt lgkmcnt(0)" ::: "memory");
    __builtin_amdgcn_s_barrier();
    __builtin_amdgcn_sched_barrier(0);
}

// ---------------------------------------------------------------------------
// fp32 -> bf16 bulk convert (8 elems/thread)
// ---------------------------------------------------------------------------
__global__ __launch_bounds__(256)
void convert_kernel(const float* __restrict__ src, unsigned short* __restrict__ dst, int n)
{
    int i = (blockIdx.x * 256 + threadIdx.x) * 8;
    if (i >= n) return;
    float4 f0 = *(const float4*)&src[i];
    float4 f1 = *(const float4*)&src[i + 4];
    uint4 o;
    o.x = f2bf(f0.x) | ((unsigned)f2bf(f0.y) << 16);
    o.y = f2bf(f0.z) | ((unsigned)f2bf(f0.w) << 16);
    o.z = f2bf(f1.x) | ((unsigned)f2bf(f1.y) << 16);
    o.w = f2bf(f1.z) | ((unsigned)f2bf(f1.w) << 16);
    *(uint4*)&dst[i] = o;
}

// ---------------------------------------------------------------------------
// Fused Q/K/V projection, bf16 MFMA, software-pipelined staging.
// 128x128 tile, BK=32, 4 waves.  Grid (24,64); blockIdx.x>>3 selects W.
// Q: RoPE * 1/8 -> (B,H,S,DK).  K: RoPE -> (B,H,S,DK).  V: (B,H,DK,S).
// ---------------------------------------------------------------------------
__global__ __launch_bounds__(256)
void proj_qkv_kernel(const unsigned short* __restrict__ Xb,
                     const unsigned short* __restrict__ Wqb,
                     const unsigned short* __restrict__ Wkb,
                     const unsigned short* __restrict__ Wvb,
                     const int* __restrict__ pos,
                     unsigned short* __restrict__ Qb,
                     unsigned short* __restrict__ Kb,
                     unsigned short* __restrict__ Vtb)
{
    __shared__ short As[128][40];   // [m][k] bf16 (+8 pad)
    __shared__ short Bs[128][40];   // [n][k]

    const int t  = threadIdx.x;
    const int l  = t & 63;
    const int w  = t >> 6;
    const int wr = w >> 1, wc = w & 1;
    const int lm = l & 15;
    const int lk = (l >> 4) * 8;

    const int nb   = blockIdx.x;
    const int wsel = nb >> 3;
    const int n0   = (nb & 7) * 128;
    const int m0   = blockIdx.y * 128;
    const unsigned short* W = (wsel == 0) ? Wqb : (wsel == 1) ? Wkb : Wvb;

    const int sr = t >> 2;        // 0..63
    const int sc = (t & 3) * 8;   // 0,8,16,24

    f32x4 acc[4][4];
#pragma unroll
    for (int i = 0; i < 4; ++i)
#pragma unroll
        for (int j = 0; j < 4; ++j) acc[i][j] = (f32x4){0.f, 0.f, 0.f, 0.f};

    // prefetch tile 0
    uint4 a0 = *(const uint4*)&Xb[(size_t)(m0 + sr)      * D_DIM + sc];
    uint4 a1 = *(const uint4*)&Xb[(size_t)(m0 + sr + 64) * D_DIM + sc];
    uint4 b0 = *(const uint4*)&W [(size_t)(n0 + sr)      * D_DIM + sc];
    uint4 b1 = *(const uint4*)&W [(size_t)(n0 + sr + 64) * D_DIM + sc];

    for (int k0 = 0; k0 < D_DIM; k0 += 32) {
        __syncthreads();                       // (A) prev compute done with LDS
        *(uint4*)&As[sr][sc]      = a0;
        *(uint4*)&As[sr + 64][sc] = a1;
        *(uint4*)&Bs[sr][sc]      = b0;
        *(uint4*)&Bs[sr + 64][sc] = b1;
        if (k0 + 32 < D_DIM) {                 // issue next tile; hides under MFMA
            a0 = *(const uint4*)&Xb[(size_t)(m0 + sr)      * D_DIM + k0 + 32 + sc];
            a1 = *(const uint4*)&Xb[(size_t)(m0 + sr + 64) * D_DIM + k0 + 32 + sc];
            b0 = *(const uint4*)&W [(size_t)(n0 + sr)      * D_DIM + k0 + 32 + sc];
            b1 = *(const uint4*)&W [(size_t)(n0 + sr + 64) * D_DIM + k0 + 32 + sc];
        }
        barrier_keep_vmem();                   // (B) keeps prefetch in flight

        bf16x8 af[4], bf[4];
#pragma unroll
        for (int mt = 0; mt < 4; ++mt)
            af[mt] = *(const bf16x8*)&As[wr * 64 + mt * 16 + lm][lk];
#pragma unroll
        for (int nt = 0; nt < 4; ++nt)
            bf[nt] = *(const bf16x8*)&Bs[wc * 64 + nt * 16 + lm][lk];
#pragma unroll
        for (int mt = 0; mt < 4; ++mt)
#pragma unroll
            for (int nt = 0; nt < 4; ++nt)
                acc[mt][nt] = MFMA16(af[mt], bf[nt], acc[mt][nt]);
    }

    // ---- epilogue ----
    int dks[4], hs[4];
#pragma unroll
    for (int nt = 0; nt < 4; ++nt) {
        int col = n0 + wc * 64 + nt * 16 + lm;
        dks[nt] = col & 63;
        hs[nt]  = col >> 6;
    }

    if (wsel < 2) {   // Q or K: RoPE then (B,H,S,DK); Q also folds 1/sqrt(DK)
        unsigned short* Out = (wsel == 0) ? Qb : Kb;
        const float oscale = (wsel == 0) ? 0.125f : 1.0f;
        float invf[4];
#pragma unroll
        for (int nt = 0; nt < 4; ++nt)
            invf[nt] = exp2f((float)(dks[nt] >> 1) * -0.4152410119f);  // 10000^(-ip/32)
#pragma unroll
        for (int mt = 0; mt < 4; ++mt)
#pragma unroll
            for (int rg = 0; rg < 4; ++rg) {
                int m = m0 + wr * 64 + mt * 16 + ((l >> 4) << 2) + rg;
                int b = m >> 11, s = m & (S_LEN - 1);
                float pf = (float)pos[s];
#pragma unroll
                for (int nt = 0; nt < 4; ++nt) {
                    float sn, cn;
                    __sincosf(pf * invf[nt], &sn, &cn);
                    float val  = acc[mt][nt][rg];
                    float part = __shfl_xor(val, 1);   // adjacent col = RoPE partner
                    float res  = ((dks[nt] & 1) == 0) ? val * cn - part * sn
                                                      : part * sn + val * cn;
                    Out[((size_t)(b * NHEAD + hs[nt]) * S_LEN + s) * HDK + dks[nt]] =
                        f2bf(res * oscale);
                }
            }
    } else {          // V: transposed (B,H,DK,S)
#pragma unroll
        for (int mt = 0; mt < 4; ++mt)
#pragma unroll
            for (int rg = 0; rg < 4; ++rg) {
                int m = m0 + wr * 64 + mt * 16 + ((l >> 4) << 2) + rg;
                int b = m >> 11, s = m & (S_LEN - 1);
#pragma unroll
                for (int nt = 0; nt < 4; ++nt)
                    Vtb[((size_t)(b * NHEAD + hs[nt]) * HDK + dks[nt]) * S_LEN + s] =
                        f2bf(acc[mt][nt][rg]);
            }
    }
}

// ---------------------------------------------------------------------------
// Causal flash attention, bf16 MFMA, pipelined.  Block = 128 q-rows of one
// (b,h), 8 waves (512 thr); wave w owns q-rows w*16..w*16+15.  KV tiles 64.
// K/V prefetched to regs across a vmcnt-preserving barrier.  P staged through
// wave-private LDS rows aliased onto the dead Q tile.
// LDS: QPs 128x72 + Ks 64x72 + Vts 64x72 = 36,864 B.
// ---------------------------------------------------------------------------
__global__ __launch_bounds__(512)
void attn_kernel(const unsigned short* __restrict__ Q,
                 const unsigned short* __restrict__ K,
                 const unsigned short* __restrict__ Vt,
                 unsigned short* __restrict__ AO)
{
    __shared__ short QPs[128][72];  // prologue: Q [r][d]; loop: P [r][kcol]
    __shared__ short Ks[64][72];    // [kvrow][d]
    __shared__ short Vts[64][72];   // [d][kvrow]

    const int t  = threadIdx.x;
    const int l  = t & 63;
    const int w  = t >> 6;          // 0..7
    const int lm = l & 15;
    const int u  = l >> 4;          // 0..3
    const int lk = u * 8;
    const int qi = blockIdx.x, bh = blockIdx.y;

    const unsigned short* Qbh  = Q  + (size_t)bh * S_LEN * HDK;
    const unsigned short* Kbh  = K  + (size_t)bh * S_LEN * HDK;
    const unsigned short* Vtbh = Vt + (size_t)bh * S_LEN * HDK;

    const int r0 = t >> 3;        // 0..63
    const int ch = (t & 7) * 8;   // 0..56

    {   // stage Q tile [128][64]
        uint4 q0 = *(const uint4*)&Qbh[(size_t)(qi * 128 + r0)      * HDK + ch];
        uint4 q1 = *(const uint4*)&Qbh[(size_t)(qi * 128 + r0 + 64) * HDK + ch];
        *(uint4*)&QPs[r0][ch]      = q0;
        *(uint4*)&QPs[r0 + 64][ch] = q1;
    }
    __syncthreads();

    bf16x8 aq[2];   // Q A-frags (scale pre-folded in projection)
#pragma unroll
    for (int ks = 0; ks < 2; ++ks)
        aq[ks] = *(const bf16x8*)&QPs[w * 16 + lm][ks * 32 + lk];

    f32x4 o4[4];
#pragma unroll
    for (int dt = 0; dt < 4; ++dt) o4[dt] = (f32x4){0.f, 0.f, 0.f, 0.f};
    float mrow[4] = {-__builtin_inff(), -__builtin_inff(), -__builtin_inff(), -__builtin_inff()};
    float lrow[4] = {0.f, 0.f, 0.f, 0.f};

    const int ktmax = 2 * qi + 1;
    uint4 kreg = *(const uint4*)&Kbh [(size_t)r0 * HDK + ch];
    uint4 vreg = *(const uint4*)&Vtbh[(size_t)r0 * S_LEN + ch];

    for (int kt = 0; kt <= ktmax; ++kt) {
        __syncthreads();   // (A) all waves done reading Ks/Vts/QPs of prev iter
        *(uint4*)&Ks[r0][ch]  = kreg;
        *(uint4*)&Vts[r0][ch] = vreg;
        if (kt < ktmax) {  // prefetch next tile; latency hides under compute
            kreg = *(const uint4*)&Kbh [(size_t)((kt + 1) * 64 + r0) * HDK + ch];
            vreg = *(const uint4*)&Vtbh[(size_t)r0 * S_LEN + (kt + 1) * 64 + ch];
        }
        barrier_keep_vmem();   // (B)

        // S = Q K^T : wave computes 16x64
        f32x4 sacc[4];
#pragma unroll
        for (int nt = 0; nt < 4; ++nt) sacc[nt] = (f32x4){0.f, 0.f, 0.f, 0.f};
#pragma unroll
        for (int nt = 0; nt < 4; ++nt)
#pragma unroll
            for (int ks = 0; ks < 2; ++ks) {
                bf16x8 bk = *(const bf16x8*)&Ks[nt * 16 + lm][ks * 32 + lk];
                sacc[nt] = MFMA16(aq[ks], bk, sacc[nt]);
            }

        // online softmax (per lane: 4 rows x 4 cols); mask only near diagonal
        const bool maskt = (kt * 64 + 63) > (qi * 128 + w * 16);
#pragma unroll
        for (int rg = 0; rg < 4; ++rg) {
            const int row_g = qi * 128 + w * 16 + u * 4 + rg;
            float sv[4];
#pragma unroll
            for (int nt = 0; nt < 4; ++nt) {
                float x = sacc[nt][rg];
                if (maskt && (kt * 64 + nt * 16 + lm) > row_g) x = -__builtin_inff();
                sv[nt] = x;
            }
            float rm = fmaxf(fmaxf(sv[0], sv[1]), fmaxf(sv[2], sv[3]));
            rm = fmaxf(rm, __shfl_xor(rm, 1));
            rm = fmaxf(rm, __shfl_xor(rm, 2));
            rm = fmaxf(rm, __shfl_xor(rm, 4));
            rm = fmaxf(rm, __shfl_xor(rm, 8));
            const float mnew = fmaxf(mrow[rg], rm);     // finite from kt=0 on
            const float corr = __expf(mrow[rg] - mnew); // exp(-inf)=0 first iter
            float pv[4], psum = 0.f;
#pragma unroll
            for (int nt = 0; nt < 4; ++nt) { pv[nt] = __expf(sv[nt] - mnew); psum += pv[nt]; }
            psum += __shfl_xor(psum, 1);
            psum += __shfl_xor(psum, 2);
            psum += __shfl_xor(psum, 4);
            psum += __shfl_xor(psum, 8);
            lrow[rg] = lrow[rg] * corr + psum;
            mrow[rg] = mnew;
#pragma unroll
            for (int dt = 0; dt < 4; ++dt) o4[dt][rg] *= corr;
            // stage P (bf16) into wave-private rows of QPs
#pragma unroll
            for (int nt = 0; nt < 4; ++nt)
                QPs[w * 16 + u * 4 + rg][nt * 16 + lm] = (short)f2bf(pv[nt]);
        }

        // O += P V  (wave-private P rows; same-wave DS RAW is in-order)
#pragma unroll
        for (int ks = 0; ks < 2; ++ks) {
            bf16x8 ap = *(const bf16x8*)&QPs[w * 16 + lm][ks * 32 + lk];
#pragma unroll
            for (int dt = 0; dt < 4; ++dt) {
                bf16x8 bv = *(const bf16x8*)&Vts[dt * 16 + lm][ks * 32 + lk];
                o4[dt] = MFMA16(ap, bv, o4[dt]);
            }
        }
    }

    // epilogue: AO (B,S,D) bf16
    const int b = bh >> 4, h = bh & 15;
#pragma unroll
    for (int rg = 0; rg < 4; ++rg) {
        const int row_g = qi * 128 + w * 16 + u * 4 + rg;
        const float il = 1.0f / lrow[rg];
#pragma unroll
        for (int dt = 0; dt < 4; ++dt)
            AO[((size_t)(b * S_LEN + row_g)) * D_DIM + h * HDK + dt * 16 + lm] =
                f2bf(o4[dt][rg] * il);
    }
}

// ---------------------------------------------------------------------------
// Final projection: out = AO @ Wo^T, bf16 MFMA, pipelined, fp32 out.
// ---------------------------------------------------------------------------
__global__ __launch_bounds__(256)
void proj_out_kernel(const unsigned short* __restrict__ Ab,
                     const unsigned short* __restrict__ Wob,
                     float* __restrict__ out)
{
    __shared__ short As[128][40];
    __shared__ short Bs[128][40];

    const int t  = threadIdx.x;
    const int l  = t & 63;
    const int w  = t >> 6;
    const int wr = w >> 1, wc = w & 1;
    const int lm = l & 15;
    const int lk = (l >> 4) * 8;
    const int n0 = blockIdx.x * 128;
    const int m0 = blockIdx.y * 128;
    const int sr = t >> 2;
    const int sc = (t & 3) * 8;

    f32x4 acc[4][4];
#pragma unroll
    for (int i = 0; i < 4; ++i)
#pragma unroll
        for (int j = 0; j < 4; ++j) acc[i][j] = (f32x4){0.f, 0.f, 0.f, 0.f};

    uint4 a0 = *(const uint4*)&Ab [(size_t)(m0 + sr)      * D_DIM + sc];
    uint4 a1 = *(const uint4*)&Ab [(size_t)(m0 + sr + 64) * D_DIM + sc];
    uint4 b0 = *(const uint4*)&Wob[(size_t)(n0 + sr)      * D_DIM + sc];
    uint4 b1 = *(const uint4*)&Wob[(size_t)(n0 + sr + 64) * D_DIM + sc];

    for (int k0 = 0; k0 < D_DIM; k0 += 32) {
        __syncthreads();
        *(uint4*)&As[sr][sc]      = a0;
        *(uint4*)&As[sr + 64][sc] = a1;
        *(uint4*)&Bs[sr][sc]      = b0;
        *(uint4*)&Bs[sr + 64][sc] = b1;
        if (k0 + 32 < D_DIM) {
            a0 = *(const uint4*)&Ab [(size_t)(m0 + sr)      * D_DIM + k0 + 32 + sc];
            a1 = *(const uint4*)&Ab [(size_t)(m0 + sr + 64) * D_DIM + k0 + 32 + sc];
            b0 = *(const uint4*)&Wob[(size_t)(n0 + sr)      * D_DIM + k0 + 32 + sc];
            b1 = *(const uint4*)&Wob[(size_t)(n0 + sr + 64) * D_DIM + k0 + 32 + sc];
        }
        barrier_keep_vmem();

        bf16x8 af[4], bf[4];
#pragma unroll
        for (int mt = 0; mt < 4; ++mt)
            af[mt] = *(const bf16x8*)&As[wr * 64 + mt * 16 + lm][lk];
#pragma unroll
        for (int nt = 0; nt < 4; ++nt)
            bf[nt] = *(const bf16x8*)&Bs[wc * 64 + nt * 16 + lm][lk];
#pragma unroll
        for (int mt = 0; mt < 4; ++mt)
#pragma unroll
            for (int nt = 0; nt < 4; ++nt)
                acc[mt][nt] = MFMA16(af[mt], bf[nt], acc[mt][nt]);
    }

#pragma unroll
    for (int mt = 0; mt < 4; ++mt)
#pragma unroll
        for (int rg = 0; rg < 4; ++rg) {
            int m = m0 + wr * 64 + mt * 16 + ((l >> 4) << 2) + rg;
#pragma unroll
            for (int nt = 0; nt < 4; ++nt)
                out[(size_t)m * D_DIM + n0 + wc * 64 + nt * 16 + lm] = acc[mt][nt][rg];
        }
}

// ---------------------------------------------------------------------------
extern "C" void kernel_launch(void* const* d_in, const int* in_sizes, int n_in,
                              void* d_out, int out_size, void* d_ws, size_t ws_size,
                              hipStream_t stream)
{
    const float* x   = (const float*)d_in[0];
    const float* Wq  = (const float*)d_in[1];
    const float* Wk  = (const float*)d_in[2];
    const float* Wv  = (const float*)d_in[3];
    const float* Wo  = (const float*)d_in[4];
    const int*   pos = (const int*)d_in[5];
    float* out = (float*)d_out;

    const size_t NX = (size_t)NBATCH * S_LEN * D_DIM;   // 8,388,608
    const size_t NW = (size_t)D_DIM * D_DIM;            // 1,048,576

    unsigned short* Xb  = (unsigned short*)d_ws;        // ws total: 88 MB
    unsigned short* Wqb = Xb  + NX;
    unsigned short* Wkb = Wqb + NW;
    unsigned short* Wvb = Wkb + NW;
    unsigned short* Wob = Wvb + NW;
    unsigned short* Qb  = Wob + NW;
    unsigned short* Kb  = Qb  + NX;
    unsigned short* Vtb = Kb  + NX;
    unsigned short* AOb = Vtb + NX;

    dim3 blk(256);
    convert_kernel<<<dim3(4096), blk, 0, stream>>>(x,  Xb,  (int)NX);
    convert_kernel<<<dim3(512),  blk, 0, stream>>>(Wq, Wqb, (int)NW);
    convert_kernel<<<dim3(512),  blk, 0, stream>>>(Wk, Wkb, (int)NW);
    convert_kernel<<<dim3(512),  blk, 0, stream>>>(Wv, Wvb, (int)NW);
    convert_kernel<<<dim3(512),  blk, 0, stream>>>(Wo, Wob, (int)NW);

    proj_qkv_kernel<<<dim3(24, 64), blk, 0, stream>>>(Xb, Wqb, Wkb, Wvb, pos, Qb, Kb, Vtb);

    attn_kernel<<<dim3(S_LEN / 128, NBATCH * NHEAD), dim3(512), 0, stream>>>(Qb, Kb, Vtb, AOb);

    proj_out_kernel<<<dim3(8, 64), blk, 0, stream>>>(AOb, Wob, out);
}

// Round 10
// 313.122 us; speedup vs baseline: 6.8456x; 1.2809x over previous
//
#include <hip/hip_runtime.h>
#include <math.h>

#define S_LEN  2048
#define D_DIM  1024
#define NHEAD  16
#define HDK    64
#define NBATCH 4

typedef __attribute__((ext_vector_type(8))) short bf16x8;   // 8 bf16 (4 VGPRs)
typedef __attribute__((ext_vector_type(4))) float f32x4;    // MFMA C/D

#define MFMA16(a, b, c) __builtin_amdgcn_mfma_f32_16x16x32_bf16((a), (b), (c), 0, 0, 0)

// MFMA 16x16x32 layouts (guide §3, m89/m91-verified):
//   A-frag: lane holds row (l&15), k = (l>>4)*8 + i (8 contiguous bf16)
//   B-frag: lane holds col (l&15), k = (l>>4)*8 + i
//   C/D:    lane holds col (l&15), row = (l>>4)*4 + reg

__device__ __forceinline__ unsigned short f2bf(float f) {   // RNE float->bf16
    unsigned u = __float_as_uint(f);
    u += 0x7fffu + ((u >> 16) & 1u);
    return (unsigned short)(u >> 16);
}

// Barrier that does NOT drain vmcnt: global->reg prefetches stay in flight.
// lgkmcnt(0) makes this wave's ds ops visible/complete first.  Safe when the
// only unwaited memory ops are loads to private VGPRs / stores nobody reads.
__device__ __forceinline__ void barrier_keep_vmem() {
    asm volatile("s_waitcnt lgkmcnt(0)" ::: "memory");
    __builtin_amdgcn_s_barrier();
    __builtin_amdgcn_sched_barrier(0);
}

// ---------------------------------------------------------------------------
// fp32 -> bf16 bulk convert (8 elems/thread)
// ---------------------------------------------------------------------------
__global__ __launch_bounds__(256)
void convert_kernel(const float* __restrict__ src, unsigned short* __restrict__ dst, int n)
{
    int i = (blockIdx.x * 256 + threadIdx.x) * 8;
    if (i >= n) return;
    float4 f0 = *(const float4*)&src[i];
    float4 f1 = *(const float4*)&src[i + 4];
    uint4 o;
    o.x = f2bf(f0.x) | ((unsigned)f2bf(f0.y) << 16);
    o.y = f2bf(f0.z) | ((unsigned)f2bf(f0.w) << 16);
    o.z = f2bf(f1.x) | ((unsigned)f2bf(f1.y) << 16);
    o.w = f2bf(f1.z) | ((unsigned)f2bf(f1.w) << 16);
    *(uint4*)&dst[i] = o;
}

// ---------------------------------------------------------------------------
// Fused Q/K/V projection, bf16 MFMA, software-pipelined staging.
// 128x128 tile, BK=32, 4 waves.  Grid (24,64); blockIdx.x>>3 selects W.
// Q: RoPE * 1/8 -> (B,H,S,DK).  K: RoPE -> (B,H,S,DK).  V: (B,H,DK,S).
// ---------------------------------------------------------------------------
__global__ __launch_bounds__(256)
void proj_qkv_kernel(const unsigned short* __restrict__ Xb,
                     const unsigned short* __restrict__ Wqb,
                     const unsigned short* __restrict__ Wkb,
                     const unsigned short* __restrict__ Wvb,
                     const int* __restrict__ pos,
                     unsigned short* __restrict__ Qb,
                     unsigned short* __restrict__ Kb,
                     unsigned short* __restrict__ Vtb)
{
    __shared__ short As[128][40];   // [m][k] bf16 (+8 pad)
    __shared__ short Bs[128][40];   // [n][k]

    const int t  = threadIdx.x;
    const int l  = t & 63;
    const int w  = t >> 6;
    const int wr = w >> 1, wc = w & 1;
    const int lm = l & 15;
    const int lk = (l >> 4) * 8;

    const int nb   = blockIdx.x;
    const int wsel = nb >> 3;
    const int n0   = (nb & 7) * 128;
    const int m0   = blockIdx.y * 128;
    const unsigned short* W = (wsel == 0) ? Wqb : (wsel == 1) ? Wkb : Wvb;

    const int sr = t >> 2;        // 0..63
    const int sc = (t & 3) * 8;   // 0,8,16,24

    f32x4 acc[4][4];
#pragma unroll
    for (int i = 0; i < 4; ++i)
#pragma unroll
        for (int j = 0; j < 4; ++j) acc[i][j] = (f32x4){0.f, 0.f, 0.f, 0.f};

    // prefetch tile 0
    uint4 a0 = *(const uint4*)&Xb[(size_t)(m0 + sr)      * D_DIM + sc];
    uint4 a1 = *(const uint4*)&Xb[(size_t)(m0 + sr + 64) * D_DIM + sc];
    uint4 b0 = *(const uint4*)&W [(size_t)(n0 + sr)      * D_DIM + sc];
    uint4 b1 = *(const uint4*)&W [(size_t)(n0 + sr + 64) * D_DIM + sc];

    for (int k0 = 0; k0 < D_DIM; k0 += 32) {
        __syncthreads();                       // (A) prev compute done with LDS
        *(uint4*)&As[sr][sc]      = a0;
        *(uint4*)&As[sr + 64][sc] = a1;
        *(uint4*)&Bs[sr][sc]      = b0;
        *(uint4*)&Bs[sr + 64][sc] = b1;
        if (k0 + 32 < D_DIM) {                 // issue next tile; hides under MFMA
            a0 = *(const uint4*)&Xb[(size_t)(m0 + sr)      * D_DIM + k0 + 32 + sc];
            a1 = *(const uint4*)&Xb[(size_t)(m0 + sr + 64) * D_DIM + k0 + 32 + sc];
            b0 = *(const uint4*)&W [(size_t)(n0 + sr)      * D_DIM + k0 + 32 + sc];
            b1 = *(const uint4*)&W [(size_t)(n0 + sr + 64) * D_DIM + k0 + 32 + sc];
        }
        barrier_keep_vmem();                   // (B) keeps prefetch in flight

        bf16x8 af[4], bf[4];
#pragma unroll
        for (int mt = 0; mt < 4; ++mt)
            af[mt] = *(const bf16x8*)&As[wr * 64 + mt * 16 + lm][lk];
#pragma unroll
        for (int nt = 0; nt < 4; ++nt)
            bf[nt] = *(const bf16x8*)&Bs[wc * 64 + nt * 16 + lm][lk];
#pragma unroll
        for (int mt = 0; mt < 4; ++mt)
#pragma unroll
            for (int nt = 0; nt < 4; ++nt)
                acc[mt][nt] = MFMA16(af[mt], bf[nt], acc[mt][nt]);
    }

    // ---- epilogue ----
    int dks[4], hs[4];
#pragma unroll
    for (int nt = 0; nt < 4; ++nt) {
        int col = n0 + wc * 64 + nt * 16 + lm;
        dks[nt] = col & 63;
        hs[nt]  = col >> 6;
    }

    if (wsel < 2) {   // Q or K: RoPE then (B,H,S,DK); Q also folds 1/sqrt(DK)
        unsigned short* Out = (wsel == 0) ? Qb : Kb;
        const float oscale = (wsel == 0) ? 0.125f : 1.0f;
        float invf[4];
#pragma unroll
        for (int nt = 0; nt < 4; ++nt)
            invf[nt] = exp2f((float)(dks[nt] >> 1) * -0.4152410119f);  // 10000^(-ip/32)
#pragma unroll
        for (int mt = 0; mt < 4; ++mt)
#pragma unroll
            for (int rg = 0; rg < 4; ++rg) {
                int m = m0 + wr * 64 + mt * 16 + ((l >> 4) << 2) + rg;
                int b = m >> 11, s = m & (S_LEN - 1);
                float pf = (float)pos[s];
#pragma unroll
                for (int nt = 0; nt < 4; ++nt) {
                    float sn, cn;
                    __sincosf(pf * invf[nt], &sn, &cn);
                    float val  = acc[mt][nt][rg];
                    float part = __shfl_xor(val, 1);   // adjacent col = RoPE partner
                    float res  = ((dks[nt] & 1) == 0) ? val * cn - part * sn
                                                      : part * sn + val * cn;
                    Out[((size_t)(b * NHEAD + hs[nt]) * S_LEN + s) * HDK + dks[nt]] =
                        f2bf(res * oscale);
                }
            }
    } else {          // V: transposed (B,H,DK,S)
#pragma unroll
        for (int mt = 0; mt < 4; ++mt)
#pragma unroll
            for (int rg = 0; rg < 4; ++rg) {
                int m = m0 + wr * 64 + mt * 16 + ((l >> 4) << 2) + rg;
                int b = m >> 11, s = m & (S_LEN - 1);
#pragma unroll
                for (int nt = 0; nt < 4; ++nt)
                    Vtb[((size_t)(b * NHEAD + hs[nt]) * HDK + dks[nt]) * S_LEN + s] =
                        f2bf(acc[mt][nt][rg]);
            }
    }
}

// ---------------------------------------------------------------------------
// Causal flash attention, bf16 MFMA, work-balanced.  Block = TWO 128-row
// q-tiles (qp and 15-qp) of one (b,h) -> every block runs exactly
// (2qp+2)+(2(15-qp)+2) = 34 K-tile iterations: no causal tail imbalance.
// 8 waves (512 thr); wave w owns q-rows w*16..w*16+15 of the current tile.
// K/V prefetched to regs; ALL barriers are lgkm-only (no vmcnt drain — no
// cross-thread dependency needs it), so prefetches span barriers.
// P staged through wave-private LDS rows aliased onto the dead Q tile.
// LDS: QPs 128x72 + Ks 64x72 + Vts 64x72 = 36,864 B.
// ---------------------------------------------------------------------------
__global__ __launch_bounds__(512)
void attn_kernel(const unsigned short* __restrict__ Q,
                 const unsigned short* __restrict__ K,
                 const unsigned short* __restrict__ Vt,
                 unsigned short* __restrict__ AO)
{
    __shared__ short QPs[128][72];  // phase start: Q [r][d]; loop: P [r][kcol]
    __shared__ short Ks[64][72];    // [kvrow][d]
    __shared__ short Vts[64][72];   // [d][kvrow]

    const int t  = threadIdx.x;
    const int l  = t & 63;
    const int w  = t >> 6;          // 0..7
    const int lm = l & 15;
    const int u  = l >> 4;          // 0..3
    const int lk = u * 8;
    const int qp = blockIdx.x, bh = blockIdx.y;

    const unsigned short* Qbh  = Q  + (size_t)bh * S_LEN * HDK;
    const unsigned short* Kbh  = K  + (size_t)bh * S_LEN * HDK;
    const unsigned short* Vtbh = Vt + (size_t)bh * S_LEN * HDK;

    const int r0 = t >> 3;        // 0..63
    const int ch = (t & 7) * 8;   // 0..56
    const int b  = bh >> 4, h = bh & 15;

    for (int ph = 0; ph < 2; ++ph) {
        const int qi    = ph ? (15 - qp) : qp;
        const int ktmax = 2 * qi + 1;

        // Q loads first (so the staging ds_write's vmcnt wait doesn't cover
        // the K/V prefetch issued after them)
        uint4 q0 = *(const uint4*)&Qbh[(size_t)(qi * 128 + r0)      * HDK + ch];
        uint4 q1 = *(const uint4*)&Qbh[(size_t)(qi * 128 + r0 + 64) * HDK + ch];
        uint4 kreg = *(const uint4*)&Kbh [(size_t)r0 * HDK + ch];
        uint4 vreg = *(const uint4*)&Vtbh[(size_t)r0 * S_LEN + ch];

        barrier_keep_vmem();        // prev phase done reading QPs/Ks/Vts
        *(uint4*)&QPs[r0][ch]      = q0;
        *(uint4*)&QPs[r0 + 64][ch] = q1;
        barrier_keep_vmem();        // Q visible; kreg/vreg still in flight

        bf16x8 aq[2];               // Q A-frags (1/8 scale pre-folded)
#pragma unroll
        for (int ks = 0; ks < 2; ++ks)
            aq[ks] = *(const bf16x8*)&QPs[w * 16 + lm][ks * 32 + lk];

        f32x4 o4[4];
#pragma unroll
        for (int dt = 0; dt < 4; ++dt) o4[dt] = (f32x4){0.f, 0.f, 0.f, 0.f};
        float mrow[4] = {-__builtin_inff(), -__builtin_inff(),
                         -__builtin_inff(), -__builtin_inff()};
        float lrow[4] = {0.f, 0.f, 0.f, 0.f};

        for (int kt = 0; kt <= ktmax; ++kt) {
            barrier_keep_vmem();    // (A) prev iter's Ks/Vts/P reads done
            *(uint4*)&Ks[r0][ch]  = kreg;   // vmcnt waits are data-dependency
            *(uint4*)&Vts[r0][ch] = vreg;
            if (kt < ktmax) {       // prefetch next tile under compute
                kreg = *(const uint4*)&Kbh [(size_t)((kt + 1) * 64 + r0) * HDK + ch];
                vreg = *(const uint4*)&Vtbh[(size_t)r0 * S_LEN + (kt + 1) * 64 + ch];
            }
            barrier_keep_vmem();    // (B)

            // S = Q K^T : wave computes 16x64
            f32x4 sacc[4];
#pragma unroll
            for (int nt = 0; nt < 4; ++nt) sacc[nt] = (f32x4){0.f, 0.f, 0.f, 0.f};
#pragma unroll
            for (int nt = 0; nt < 4; ++nt)
#pragma unroll
                for (int ks = 0; ks < 2; ++ks) {
                    bf16x8 bk = *(const bf16x8*)&Ks[nt * 16 + lm][ks * 32 + lk];
                    sacc[nt] = MFMA16(aq[ks], bk, sacc[nt]);
                }

            // online softmax (per lane: 4 rows x 4 cols); mask only near diag
            const bool maskt = (kt * 64 + 63) > (qi * 128 + w * 16);
#pragma unroll
            for (int rg = 0; rg < 4; ++rg) {
                const int row_g = qi * 128 + w * 16 + u * 4 + rg;
                float sv[4];
#pragma unroll
                for (int nt = 0; nt < 4; ++nt) {
                    float x = sacc[nt][rg];
                    if (maskt && (kt * 64 + nt * 16 + lm) > row_g) x = -__builtin_inff();
                    sv[nt] = x;
                }
                float rm = fmaxf(fmaxf(sv[0], sv[1]), fmaxf(sv[2], sv[3]));
                rm = fmaxf(rm, __shfl_xor(rm, 1));
                rm = fmaxf(rm, __shfl_xor(rm, 2));
                rm = fmaxf(rm, __shfl_xor(rm, 4));
                rm = fmaxf(rm, __shfl_xor(rm, 8));
                const float mnew = fmaxf(mrow[rg], rm);
                const float corr = __expf(mrow[rg] - mnew);   // exp(-inf)=0 @kt0
                float pv[4], psum = 0.f;
#pragma unroll
                for (int nt = 0; nt < 4; ++nt) { pv[nt] = __expf(sv[nt] - mnew); psum += pv[nt]; }
                psum += __shfl_xor(psum, 1);
                psum += __shfl_xor(psum, 2);
                psum += __shfl_xor(psum, 4);
                psum += __shfl_xor(psum, 8);
                lrow[rg] = lrow[rg] * corr + psum;
                mrow[rg] = mnew;
#pragma unroll
                for (int dt = 0; dt < 4; ++dt) o4[dt][rg] *= corr;
                // stage P (bf16) into wave-private rows of QPs
#pragma unroll
                for (int nt = 0; nt < 4; ++nt)
                    QPs[w * 16 + u * 4 + rg][nt * 16 + lm] = (short)f2bf(pv[nt]);
            }

            // O += P V  (wave-private P rows; same-wave DS RAW is in-order)
#pragma unroll
            for (int ks = 0; ks < 2; ++ks) {
                bf16x8 ap = *(const bf16x8*)&QPs[w * 16 + lm][ks * 32 + lk];
#pragma unroll
                for (int dt = 0; dt < 4; ++dt) {
                    bf16x8 bv = *(const bf16x8*)&Vts[dt * 16 + lm][ks * 32 + lk];
                    o4[dt] = MFMA16(ap, bv, o4[dt]);
                }
            }
        }

        // phase epilogue: AO (B,S,D) bf16
#pragma unroll
        for (int rg = 0; rg < 4; ++rg) {
            const int row_g = qi * 128 + w * 16 + u * 4 + rg;
            const float il = 1.0f / lrow[rg];
#pragma unroll
            for (int dt = 0; dt < 4; ++dt)
                AO[((size_t)(b * S_LEN + row_g)) * D_DIM + h * HDK + dt * 16 + lm] =
                    f2bf(o4[dt][rg] * il);
        }
    }
}

// ---------------------------------------------------------------------------
// Final projection: out = AO @ Wo^T, bf16 MFMA, pipelined, fp32 out.
// ---------------------------------------------------------------------------
__global__ __launch_bounds__(256)
void proj_out_kernel(const unsigned short* __restrict__ Ab,
                     const unsigned short* __restrict__ Wob,
                     float* __restrict__ out)
{
    __shared__ short As[128][40];
    __shared__ short Bs[128][40];

    const int t  = threadIdx.x;
    const int l  = t & 63;
    const int w  = t >> 6;
    const int wr = w >> 1, wc = w & 1;
    const int lm = l & 15;
    const int lk = (l >> 4) * 8;
    const int n0 = blockIdx.x * 128;
    const int m0 = blockIdx.y * 128;
    const int sr = t >> 2;
    const int sc = (t & 3) * 8;

    f32x4 acc[4][4];
#pragma unroll
    for (int i = 0; i < 4; ++i)
#pragma unroll
        for (int j = 0; j < 4; ++j) acc[i][j] = (f32x4){0.f, 0.f, 0.f, 0.f};

    uint4 a0 = *(const uint4*)&Ab [(size_t)(m0 + sr)      * D_DIM + sc];
    uint4 a1 = *(const uint4*)&Ab [(size_t)(m0 + sr + 64) * D_DIM + sc];
    uint4 b0 = *(const uint4*)&Wob[(size_t)(n0 + sr)      * D_DIM + sc];
    uint4 b1 = *(const uint4*)&Wob[(size_t)(n0 + sr + 64) * D_DIM + sc];

    for (int k0 = 0; k0 < D_DIM; k0 += 32) {
        __syncthreads();
        *(uint4*)&As[sr][sc]      = a0;
        *(uint4*)&As[sr + 64][sc] = a1;
        *(uint4*)&Bs[sr][sc]      = b0;
        *(uint4*)&Bs[sr + 64][sc] = b1;
        if (k0 + 32 < D_DIM) {
            a0 = *(const uint4*)&Ab [(size_t)(m0 + sr)      * D_DIM + k0 + 32 + sc];
            a1 = *(const uint4*)&Ab [(size_t)(m0 + sr + 64) * D_DIM + k0 + 32 + sc];
            b0 = *(const uint4*)&Wob[(size_t)(n0 + sr)      * D_DIM + k0 + 32 + sc];
            b1 = *(const uint4*)&Wob[(size_t)(n0 + sr + 64) * D_DIM + k0 + 32 + sc];
        }
        barrier_keep_vmem();

        bf16x8 af[4], bf[4];
#pragma unroll
        for (int mt = 0; mt < 4; ++mt)
            af[mt] = *(const bf16x8*)&As[wr * 64 + mt * 16 + lm][lk];
#pragma unroll
        for (int nt = 0; nt < 4; ++nt)
            bf[nt] = *(const bf16x8*)&Bs[wc * 64 + nt * 16 + lm][lk];
#pragma unroll
        for (int mt = 0; mt < 4; ++mt)
#pragma unroll
            for (int nt = 0; nt < 4; ++nt)
                acc[mt][nt] = MFMA16(af[mt], bf[nt], acc[mt][nt]);
    }

#pragma unroll
    for (int mt = 0; mt < 4; ++mt)
#pragma unroll
        for (int rg = 0; rg < 4; ++rg) {
            int m = m0 + wr * 64 + mt * 16 + ((l >> 4) << 2) + rg;
#pragma unroll
            for (int nt = 0; nt < 4; ++nt)
                out[(size_t)m * D_DIM + n0 + wc * 64 + nt * 16 + lm] = acc[mt][nt][rg];
        }
}

// ---------------------------------------------------------------------------
extern "C" void kernel_launch(void* const* d_in, const int* in_sizes, int n_in,
                              void* d_out, int out_size, void* d_ws, size_t ws_size,
                              hipStream_t stream)
{
    const float* x   = (const float*)d_in[0];
    const float* Wq  = (const float*)d_in[1];
    const float* Wk  = (const float*)d_in[2];
    const float* Wv  = (const float*)d_in[3];
    const float* Wo  = (const float*)d_in[4];
    const int*   pos = (const int*)d_in[5];
    float* out = (float*)d_out;

    const size_t NX = (size_t)NBATCH * S_LEN * D_DIM;   // 8,388,608
    const size_t NW = (size_t)D_DIM * D_DIM;            // 1,048,576

    unsigned short* Xb  = (unsigned short*)d_ws;        // ws total: 88 MB
    unsigned short* Wqb = Xb  + NX;
    unsigned short* Wkb = Wqb + NW;
    unsigned short* Wvb = Wkb + NW;
    unsigned short* Wob = Wvb + NW;
    unsigned short* Qb  = Wob + NW;
    unsigned short* Kb  = Qb  + NX;
    unsigned short* Vtb = Kb  + NX;
    unsigned short* AOb = Vtb + NX;

    dim3 blk(256);
    convert_kernel<<<dim3(4096), blk, 0, stream>>>(x,  Xb,  (int)NX);
    convert_kernel<<<dim3(512),  blk, 0, stream>>>(Wq, Wqb, (int)NW);
    convert_kernel<<<dim3(512),  blk, 0, stream>>>(Wk, Wkb, (int)NW);
    convert_kernel<<<dim3(512),  blk, 0, stream>>>(Wv, Wvb, (int)NW);
    convert_kernel<<<dim3(512),  blk, 0, stream>>>(Wo, Wob, (int)NW);

    proj_qkv_kernel<<<dim3(24, 64), blk, 0, stream>>>(Xb, Wqb, Wkb, Wvb, pos, Qb, Kb, Vtb);

    attn_kernel<<<dim3(8, NBATCH * NHEAD), dim3(512), 0, stream>>>(Qb, Kb, Vtb, AOb);

    proj_out_kernel<<<dim3(8, 64), blk, 0, stream>>>(AOb, Wob, out);
}